// Round 1
// baseline (918.908 us; speedup 1.0000x reference)
//
#include <hip/hip_runtime.h>
#include <cstddef>
#include <cstdint>

// Problem dims (fixed by reference setup_inputs)
#define N_PATCH 100000
#define D_IN    1024
#define A_DIM   128
#define H_DIM   256
#define KTOP    16

// d_out layout (fp32 flat, reference return order)
#define OUT_LOGIT 0
#define OUT_EMB   1
#define OUT_FW    (1 + D_IN)             // 1025
#define OUT_TOPI  (OUT_FW + N_PATCH)     // 101025

// workspace layout (float units)
#define WS_SCORES 0
#define WS_CANDV  (N_PATCH)
#define WS_CANDI  (N_PATCH + 4096)
#define WS_ATTN   (N_PATCH + 2 * 4096)
#define WS_TOPI   (WS_ATTN + KTOP)
#define WS_EMB    (WS_TOPI + KTOP)

// stage-2a config
#define NB2A  256
#define CHUNK 391   // ceil(100000/256); 256*391 = 100096 >= N

// ---------------- Stage 1: scores = tanh(x@Wa1+ba1)@Wa2 + ba2 ----------------
#define BM 64
#define BK 32

__global__ __launch_bounds__(256) void k_scores(
    const float* __restrict__ x, const float* __restrict__ Wa1,
    const float* __restrict__ ba1, const float* __restrict__ Wa2,
    const float* __restrict__ ba2, float* __restrict__ scores)
{
    __shared__ float sX[BK][BM + 4];   // transposed x tile [d][row]; +4 keeps float4 alignment
    __shared__ float sW[BK][A_DIM];    // Wa1 tile [d][j]

    const int tid  = threadIdx.x;
    const int jg   = tid & 31;         // 32 column-groups of 4 (covers A=128)
    const int rg   = tid >> 5;         // 8 row-groups of 8 rows
    const int row0 = blockIdx.x * BM;
    const int j0   = jg * 4;

    float acc[8][4];
    #pragma unroll
    for (int m = 0; m < 8; ++m)
        #pragma unroll
        for (int n = 0; n < 4; ++n) acc[m][n] = 0.f;

    for (int k0 = 0; k0 < D_IN; k0 += BK) {
        // stage x tile (BM rows x BK d), transposed into LDS
        #pragma unroll
        for (int i = 0; i < 2; ++i) {
            int idx = tid + i * 256;        // 512 float4 slots
            int r   = idx >> 3;             // 0..63
            int d   = (idx & 7) * 4;        // 0..28
            float4 v = make_float4(0.f, 0.f, 0.f, 0.f);
            if (row0 + r < N_PATCH)
                v = *(const float4*)(x + (size_t)(row0 + r) * D_IN + k0 + d);
            sX[d + 0][r] = v.x; sX[d + 1][r] = v.y;
            sX[d + 2][r] = v.z; sX[d + 3][r] = v.w;
        }
        // stage Wa1 tile (BK x 128)
        #pragma unroll
        for (int i = 0; i < 4; ++i) {
            int idx = tid + i * 256;        // 1024 float4 slots
            int d   = idx >> 5;
            int j   = (idx & 31) * 4;
            *(float4*)&sW[d][j] = *(const float4*)(Wa1 + (size_t)(k0 + d) * A_DIM + j);
        }
        __syncthreads();

        for (int d = 0; d < BK; ++d) {
            float4 w4 = *(const float4*)&sW[d][j0];
            float4 xa = *(const float4*)&sX[d][rg * 8];
            float4 xb = *(const float4*)&sX[d][rg * 8 + 4];
            float xm[8] = {xa.x, xa.y, xa.z, xa.w, xb.x, xb.y, xb.z, xb.w};
            float wn[4] = {w4.x, w4.y, w4.z, w4.w};
            #pragma unroll
            for (int m = 0; m < 8; ++m)
                #pragma unroll
                for (int n = 0; n < 4; ++n)
                    acc[m][n] = fmaf(xm[m], wn[n], acc[m][n]);
        }
        __syncthreads();
    }

    // epilogue: +ba1, tanh, dot with Wa2, reduce over the 32 jg-lanes
    float b1[4], w2[4];
    #pragma unroll
    for (int n = 0; n < 4; ++n) { b1[n] = ba1[j0 + n]; w2[n] = Wa2[j0 + n]; }
    const float b2 = ba2[0];

    #pragma unroll
    for (int m = 0; m < 8; ++m) {
        float pm = 0.f;
        #pragma unroll
        for (int n = 0; n < 4; ++n)
            pm += tanhf(acc[m][n] + b1[n]) * w2[n];
        // reduce across 32 lanes sharing the same rows (xor masks stay inside half-wave)
        #pragma unroll
        for (int off = 16; off > 0; off >>= 1)
            pm += __shfl_xor(pm, off, 64);
        if (jg == 0) {
            int row = row0 + rg * 8 + m;
            if (row < N_PATCH) scores[row] = pm + b2;
        }
    }
}

// ---------------- Stage 2a: per-block local top-16 + zero full_weights -------
__global__ __launch_bounds__(256) void k_topk_local(
    const float* __restrict__ scores, float* __restrict__ candv,
    int* __restrict__ candi, float* __restrict__ out_fw)
{
    __shared__ float sv[512];
    __shared__ float rv[256];
    __shared__ int   rs[256];
    const int tid  = threadIdx.x;
    const int base = blockIdx.x * CHUNK;

    for (int i = tid; i < 512; i += 256) {
        int g = base + i;
        sv[i] = (i < CHUNK && g < N_PATCH) ? scores[g] : -1e30f;
    }
    for (int i = tid; i < CHUNK; i += 256) {
        int g = base + i;
        if (g < N_PATCH) out_fw[g] = 0.f;   // zero full_weights (d_out is poisoned)
    }
    __syncthreads();

    for (int r = 0; r < KTOP; ++r) {
        float v1 = sv[tid], v2 = sv[tid + 256];
        float bv; int bs;
        if (v2 > v1) { bv = v2; bs = tid + 256; } else { bv = v1; bs = tid; }
        rv[tid] = bv; rs[tid] = bs;
        __syncthreads();
        for (int off = 128; off > 0; off >>= 1) {
            if (tid < off) {
                float ov = rv[tid + off]; int os = rs[tid + off];
                if (ov > rv[tid] || (ov == rv[tid] && os < rs[tid])) {
                    rv[tid] = ov; rs[tid] = os;
                }
            }
            __syncthreads();
        }
        if (tid == 0) {
            int s = rs[0];
            candv[blockIdx.x * KTOP + r] = rv[0];
            candi[blockIdx.x * KTOP + r] = base + s;
            sv[s] = -1e30f;
        }
        __syncthreads();
    }
}

// ---------------- Stage 2b: global top-16, softmax, scatter ------------------
__global__ __launch_bounds__(256) void k_topk_global(
    const float* __restrict__ candv, const int* __restrict__ candi,
    float* __restrict__ out, float* __restrict__ ws_attn, int* __restrict__ ws_topi)
{
    __shared__ float cv[4096];
    __shared__ int   ci[4096];
    __shared__ float rv[256];
    __shared__ int   rgx[256];
    __shared__ int   rsl[256];
    __shared__ float topv[KTOP];
    __shared__ int   topi[KTOP];
    __shared__ float attn[KTOP];
    const int tid = threadIdx.x;

    for (int i = tid; i < 4096; i += 256) { cv[i] = candv[i]; ci[i] = candi[i]; }
    __syncthreads();

    for (int r = 0; r < KTOP; ++r) {
        float bv = -1e38f; int bg = 0x7fffffff; int bs = tid * 16;
        #pragma unroll
        for (int i = 0; i < 16; ++i) {
            int s = tid * 16 + i;
            float v = cv[s]; int g = ci[s];
            if (v > bv || (v == bv && g < bg)) { bv = v; bg = g; bs = s; }
        }
        rv[tid] = bv; rgx[tid] = bg; rsl[tid] = bs;
        __syncthreads();
        for (int off = 128; off > 0; off >>= 1) {
            if (tid < off) {
                if (rv[tid + off] > rv[tid] ||
                    (rv[tid + off] == rv[tid] && rgx[tid + off] < rgx[tid])) {
                    rv[tid] = rv[tid + off]; rgx[tid] = rgx[tid + off]; rsl[tid] = rsl[tid + off];
                }
            }
            __syncthreads();
        }
        if (tid == 0) {
            topv[r] = rv[0]; topi[r] = rgx[0]; cv[rsl[0]] = -1e30f;
        }
        __syncthreads();
    }

    if (tid == 0) {
        float mx = topv[0];       // descending order -> first is max
        float s = 0.f;
        for (int k2 = 0; k2 < KTOP; ++k2) {
            float e = expf(topv[k2] - mx);
            attn[k2] = e; s += e;
        }
        float inv = 1.f / s;
        for (int k2 = 0; k2 < KTOP; ++k2) attn[k2] *= inv;
    }
    __syncthreads();

    if (tid < KTOP) {
        out[OUT_TOPI + tid] = (float)topi[tid];   // top_idx as f32 (exact, < 2^24)
        out[OUT_FW + topi[tid]] = attn[tid];      // scatter (region zeroed by 2a)
        ws_attn[tid] = attn[tid];
        ws_topi[tid] = topi[tid];
    }
}

// ---------------- Stage 3: slide_embedding = attn_w @ x[top_idx] -------------
__global__ __launch_bounds__(256) void k_embed(
    const float* __restrict__ x, const float* __restrict__ attn,
    const int* __restrict__ topi, float* __restrict__ out, float* __restrict__ emb)
{
    __shared__ float a[KTOP];
    __shared__ int   ti[KTOP];
    if (threadIdx.x < KTOP) { a[threadIdx.x] = attn[threadIdx.x]; ti[threadIdx.x] = topi[threadIdx.x]; }
    __syncthreads();
    int d = blockIdx.x * 256 + threadIdx.x;   // grid = 4 blocks -> 1024 dims
    float e = 0.f;
    #pragma unroll
    for (int k2 = 0; k2 < KTOP; ++k2)
        e = fmaf(a[k2], x[(size_t)ti[k2] * D_IN + d], e);
    out[OUT_EMB + d] = e;
    emb[d] = e;
}

// ---------------- Stage 4: classifier MLP ------------------------------------
__global__ __launch_bounds__(256) void k_classifier(
    const float* __restrict__ emb, const float* __restrict__ Wc1,
    const float* __restrict__ bc1, const float* __restrict__ Wc2,
    const float* __restrict__ bc2, float* __restrict__ out)
{
    __shared__ float se[D_IN];
    __shared__ float red[256];
    const int tid = threadIdx.x;
    for (int i = tid; i < D_IN; i += 256) se[i] = emb[i];
    __syncthreads();
    float h = bc1[tid];
    for (int d = 0; d < D_IN; ++d)
        h = fmaf(se[d], Wc1[(size_t)d * H_DIM + tid], h);
    h = fmaxf(h, 0.f) * Wc2[tid];
    red[tid] = h;
    __syncthreads();
    for (int off = 128; off > 0; off >>= 1) {
        if (tid < off) red[tid] += red[tid + off];
        __syncthreads();
    }
    if (tid == 0) out[OUT_LOGIT] = red[0] + bc2[0];
}

// ---------------- Launch ------------------------------------------------------
extern "C" void kernel_launch(void* const* d_in, const int* in_sizes, int n_in,
                              void* d_out, int out_size, void* d_ws, size_t ws_size,
                              hipStream_t stream)
{
    const float* x   = (const float*)d_in[0];
    const float* Wa1 = (const float*)d_in[1];
    const float* ba1 = (const float*)d_in[2];
    const float* Wa2 = (const float*)d_in[3];
    const float* ba2 = (const float*)d_in[4];
    const float* Wc1 = (const float*)d_in[5];
    const float* bc1 = (const float*)d_in[6];
    const float* Wc2 = (const float*)d_in[7];
    const float* bc2 = (const float*)d_in[8];
    float* out = (float*)d_out;
    float* ws  = (float*)d_ws;

    float* scores = ws + WS_SCORES;
    float* candv  = ws + WS_CANDV;
    int*   candi  = (int*)(ws + WS_CANDI);
    float* attn   = ws + WS_ATTN;
    int*   topi   = (int*)(ws + WS_TOPI);
    float* emb    = ws + WS_EMB;

    dim3 blk(256);
    k_scores<<<(N_PATCH + BM - 1) / BM, blk, 0, stream>>>(x, Wa1, ba1, Wa2, ba2, scores);
    k_topk_local<<<NB2A, blk, 0, stream>>>(scores, candv, candi, out + OUT_FW);
    k_topk_global<<<1, blk, 0, stream>>>(candv, candi, out, attn, topi);
    k_embed<<<4, blk, 0, stream>>>(x, attn, topi, out, emb);
    k_classifier<<<1, blk, 0, stream>>>(emb, Wc1, bc1, Wc2, bc2, out);
}

// Round 2
// 779.548 us; speedup vs baseline: 1.1788x; 1.1788x over previous
//
#include <hip/hip_runtime.h>
#include <cstddef>
#include <cstdint>

// Problem dims (fixed by reference setup_inputs)
#define N_PATCH 100000
#define D_IN    1024
#define A_DIM   128
#define H_DIM   256
#define KTOP    16

// d_out layout (fp32 flat, reference return order)
#define OUT_LOGIT 0
#define OUT_EMB   1
#define OUT_FW    (1 + D_IN)             // 1025
#define OUT_TOPI  (OUT_FW + N_PATCH)     // 101025

// workspace layout (float units)
#define WS_SCORES 0
#define WS_CANDV  (N_PATCH)                  // 100000
#define WS_CANDI  (N_PATCH + 4096)
#define WS_ATTN   (N_PATCH + 2 * 4096)       // 108192
#define WS_TOPI   (WS_ATTN + KTOP)           // 108208
#define WS_EMB    (WS_TOPI + KTOP)           // 108224
#define WS_HPART  (WS_EMB + D_IN)            // 109248  (16*256 floats)
#define WS_WPK    (WS_HPART + 16 * H_DIM)    // 113344  (512 KB = 131072 floats), 16B-aligned

// stage-2a config
#define NB2A  256
#define CHUNK 391   // ceil(100000/256)

typedef __attribute__((ext_vector_type(8))) short bf8_t;   // 8 bf16 (4 VGPRs)
typedef __attribute__((ext_vector_type(4))) float f4_t;    // MFMA C/D frag

// ---------------- Stage 0: prepack Wa1 -> hi/lo bf16 in B-fragment layout ----
// Layout: chunk t in [0, 32768): lane=t&63, part=(t>>6)&1, nt=(t>>7)&7, ks=t>>10
// chunk holds 8 bf16: element j -> W[k = ks*32 + (lane>>4)*8 + j][n = nt*16 + (lane&15)]
__global__ __launch_bounds__(256) void k_prepack(
    const float* __restrict__ Wa1, uint4* __restrict__ wpk)
{
    int t = blockIdx.x * 256 + threadIdx.x;     // grid 128 blocks -> 32768 chunks
    int lane = t & 63;
    int part = (t >> 6) & 1;
    int nt   = (t >> 7) & 7;
    int ks   = t >> 10;
    int n  = nt * 16 + (lane & 15);
    int k0 = ks * 32 + ((lane >> 4) * 8);
    union { ushort u[8]; uint4 v; } o;
    #pragma unroll
    for (int j = 0; j < 8; ++j) {
        float w = Wa1[(size_t)(k0 + j) * A_DIM + n];
        uint b = __float_as_uint(w);
        if (part == 0) {
            o.u[j] = (ushort)(b >> 16);                       // hi (truncated bf16)
        } else {
            float hf = __uint_as_float(b & 0xffff0000u);
            o.u[j] = (ushort)(__float_as_uint(w - hf) >> 16); // lo
        }
    }
    wpk[t] = o.v;
}

// ---------------- Stage 1: scores = tanh(x@Wa1+ba1)@Wa2 + ba2 (split-bf16 MFMA)
// Block: 256 thr = 4 waves; wave covers 32 rows x 128 cols; block = 128 rows.
__device__ __forceinline__ void split8(const float4& a, const float4& b,
                                       bf8_t& hi, bf8_t& lo)
{
    float f[8] = {a.x, a.y, a.z, a.w, b.x, b.y, b.z, b.w};
    union { ushort u[8]; bf8_t v; } H, L;
    #pragma unroll
    for (int j = 0; j < 8; ++j) {
        uint t = __float_as_uint(f[j]);
        H.u[j] = (ushort)(t >> 16);
        float hf = __uint_as_float(t & 0xffff0000u);
        L.u[j] = (ushort)(__float_as_uint(f[j] - hf) >> 16);
    }
    hi = H.v; lo = L.v;
}

__global__ __launch_bounds__(256) void k_scores(
    const float* __restrict__ x, const uint4* __restrict__ wpk,
    const float* __restrict__ ba1, const float* __restrict__ Wa2,
    const float* __restrict__ ba2, float* __restrict__ scores)
{
    __shared__ uint4 sB[1024];   // 16 KB: [(nt*2+part)*64 + lane] -> 16B frag chunk

    const int tid = threadIdx.x;
    const int ln  = tid & 63;
    const int q   = ln >> 4;      // k-quad
    const int c   = ln & 15;      // col-in-tile / row-in-tile selector
    const int wv  = tid >> 6;
    const int row0 = blockIdx.x * 128 + wv * 32;

    // A-stream pointers (fragment layout: row = c, k = q*8 + j)
    const int r0 = min(row0 + c,      N_PATCH - 1);
    const int r1 = min(row0 + 16 + c, N_PATCH - 1);
    const float* pa0 = x + (size_t)r0 * D_IN + q * 8;
    const float* pa1 = x + (size_t)r1 * D_IN + q * 8;

    f4_t acc[2][8];
    #pragma unroll
    for (int rt = 0; rt < 2; ++rt)
        #pragma unroll
        for (int nt = 0; nt < 8; ++nt)
            acc[rt][nt] = (f4_t){0.f, 0.f, 0.f, 0.f};

    // register prefetch of B tile ks=0 (each thread stages 4 chunks)
    uint4 bpre[4];
    #pragma unroll
    for (int i = 0; i < 4; ++i) bpre[i] = wpk[tid + i * 256];

    for (int ks = 0; ks < 32; ++ks) {
        __syncthreads();                       // LDS free (prev reads done)
        #pragma unroll
        for (int i = 0; i < 4; ++i) sB[tid + i * 256] = bpre[i];

        // A loads for this K-step (independent of LDS)
        const float4 a0l = *(const float4*)(pa0 + ks * 32);
        const float4 a0h = *(const float4*)(pa0 + ks * 32 + 4);
        const float4 a1l = *(const float4*)(pa1 + ks * 32);
        const float4 a1h = *(const float4*)(pa1 + ks * 32 + 4);

        __syncthreads();                       // sB ready

        // prefetch next B tile into regs (in flight during MFMA)
        if (ks < 31) {
            #pragma unroll
            for (int i = 0; i < 4; ++i) bpre[i] = wpk[(ks + 1) * 1024 + tid + i * 256];
        }

        bf8_t ahi[2], alo[2];
        split8(a0l, a0h, ahi[0], alo[0]);
        split8(a1l, a1h, ahi[1], alo[1]);

        const bf8_t* sBf = (const bf8_t*)sB;
        #pragma unroll
        for (int nt = 0; nt < 8; ++nt) {
            bf8_t bh = sBf[(nt * 2 + 0) * 64 + ln];
            bf8_t bl = sBf[(nt * 2 + 1) * 64 + ln];
            acc[0][nt] = __builtin_amdgcn_mfma_f32_16x16x32_bf16(ahi[0], bh, acc[0][nt], 0, 0, 0);
            acc[0][nt] = __builtin_amdgcn_mfma_f32_16x16x32_bf16(alo[0], bh, acc[0][nt], 0, 0, 0);
            acc[0][nt] = __builtin_amdgcn_mfma_f32_16x16x32_bf16(ahi[0], bl, acc[0][nt], 0, 0, 0);
            acc[1][nt] = __builtin_amdgcn_mfma_f32_16x16x32_bf16(ahi[1], bh, acc[1][nt], 0, 0, 0);
            acc[1][nt] = __builtin_amdgcn_mfma_f32_16x16x32_bf16(alo[1], bh, acc[1][nt], 0, 0, 0);
            acc[1][nt] = __builtin_amdgcn_mfma_f32_16x16x32_bf16(ahi[1], bl, acc[1][nt], 0, 0, 0);
        }
    }

    // epilogue: +ba1, tanh, dot Wa2, reduce over the 16 lanes sharing rows
    float b1v[8], w2v[8];
    #pragma unroll
    for (int nt = 0; nt < 8; ++nt) {
        b1v[nt] = ba1[nt * 16 + c];
        w2v[nt] = Wa2[nt * 16 + c];
    }
    const float b2 = ba2[0];

    #pragma unroll
    for (int rt = 0; rt < 2; ++rt)
        #pragma unroll
        for (int reg = 0; reg < 4; ++reg) {
            float p = 0.f;
            #pragma unroll
            for (int nt = 0; nt < 8; ++nt)
                p += tanhf(acc[rt][nt][reg] + b1v[nt]) * w2v[nt];
            #pragma unroll
            for (int off = 1; off < 16; off <<= 1)
                p += __shfl_xor(p, off, 64);
            if (c == 0) {
                int row = row0 + rt * 16 + q * 4 + reg;   // C/D: row = quad*4+reg
                if (row < N_PATCH) scores[row] = p + b2;
            }
        }
}

// ---------------- Stage 2a: per-block local top-16 + zero full_weights -------
__global__ __launch_bounds__(256) void k_topk_local(
    const float* __restrict__ scores, float* __restrict__ candv,
    int* __restrict__ candi, float* __restrict__ out_fw)
{
    __shared__ float sv[512];
    __shared__ float rv[256];
    __shared__ int   rs[256];
    const int tid  = threadIdx.x;
    const int base = blockIdx.x * CHUNK;

    for (int i = tid; i < 512; i += 256) {
        int g = base + i;
        sv[i] = (i < CHUNK && g < N_PATCH) ? scores[g] : -1e30f;
    }
    for (int i = tid; i < CHUNK; i += 256) {
        int g = base + i;
        if (g < N_PATCH) out_fw[g] = 0.f;   // zero full_weights (d_out is poisoned)
    }
    __syncthreads();

    for (int r = 0; r < KTOP; ++r) {
        float v1 = sv[tid], v2 = sv[tid + 256];
        float bv; int bs;
        if (v2 > v1) { bv = v2; bs = tid + 256; } else { bv = v1; bs = tid; }
        rv[tid] = bv; rs[tid] = bs;
        __syncthreads();
        for (int off = 128; off > 0; off >>= 1) {
            if (tid < off) {
                float ov = rv[tid + off]; int os = rs[tid + off];
                if (ov > rv[tid] || (ov == rv[tid] && os < rs[tid])) {
                    rv[tid] = ov; rs[tid] = os;
                }
            }
            __syncthreads();
        }
        if (tid == 0) {
            int s = rs[0];
            candv[blockIdx.x * KTOP + r] = rv[0];
            candi[blockIdx.x * KTOP + r] = base + s;
            sv[s] = -1e30f;
        }
        __syncthreads();
    }
}

// ---------------- Stage 2b: global top-16, softmax, scatter ------------------
__global__ __launch_bounds__(256) void k_topk_global(
    const float* __restrict__ candv, const int* __restrict__ candi,
    float* __restrict__ out, float* __restrict__ ws_attn, int* __restrict__ ws_topi)
{
    __shared__ float cv[4096];
    __shared__ int   ci[4096];
    __shared__ float rv[256];
    __shared__ int   rgx[256];
    __shared__ int   rsl[256];
    __shared__ float topv[KTOP];
    __shared__ int   topi[KTOP];
    __shared__ float attn[KTOP];
    const int tid = threadIdx.x;

    for (int i = tid; i < 4096; i += 256) { cv[i] = candv[i]; ci[i] = candi[i]; }
    __syncthreads();

    for (int r = 0; r < KTOP; ++r) {
        float bv = -1e38f; int bg = 0x7fffffff; int bs = tid * 16;
        #pragma unroll
        for (int i = 0; i < 16; ++i) {
            int s = tid * 16 + i;
            float v = cv[s]; int g = ci[s];
            if (v > bv || (v == bv && g < bg)) { bv = v; bg = g; bs = s; }
        }
        rv[tid] = bv; rgx[tid] = bg; rsl[tid] = bs;
        __syncthreads();
        for (int off = 128; off > 0; off >>= 1) {
            if (tid < off) {
                if (rv[tid + off] > rv[tid] ||
                    (rv[tid + off] == rv[tid] && rgx[tid + off] < rgx[tid])) {
                    rv[tid] = rv[tid + off]; rgx[tid] = rgx[tid + off]; rsl[tid] = rsl[tid + off];
                }
            }
            __syncthreads();
        }
        if (tid == 0) {
            topv[r] = rv[0]; topi[r] = rgx[0]; cv[rsl[0]] = -1e30f;
        }
        __syncthreads();
    }

    if (tid == 0) {
        float mx = topv[0];
        float s = 0.f;
        for (int k2 = 0; k2 < KTOP; ++k2) {
            float e = expf(topv[k2] - mx);
            attn[k2] = e; s += e;
        }
        float inv = 1.f / s;
        for (int k2 = 0; k2 < KTOP; ++k2) attn[k2] *= inv;
    }
    __syncthreads();

    if (tid < KTOP) {
        out[OUT_TOPI + tid] = (float)topi[tid];
        out[OUT_FW + topi[tid]] = attn[tid];
        ws_attn[tid] = attn[tid];
        ws_topi[tid] = topi[tid];
    }
}

// ---------------- Stage 3: slide_embedding = attn_w @ x[top_idx] -------------
__global__ __launch_bounds__(256) void k_embed(
    const float* __restrict__ x, const float* __restrict__ attn,
    const int* __restrict__ topi, float* __restrict__ out, float* __restrict__ emb)
{
    __shared__ float a[KTOP];
    __shared__ int   ti[KTOP];
    if (threadIdx.x < KTOP) { a[threadIdx.x] = attn[threadIdx.x]; ti[threadIdx.x] = topi[threadIdx.x]; }
    __syncthreads();
    int d = blockIdx.x * 256 + threadIdx.x;   // grid = 4 -> 1024 dims
    float e = 0.f;
    #pragma unroll
    for (int k2 = 0; k2 < KTOP; ++k2)
        e = fmaf(a[k2], x[(size_t)ti[k2] * D_IN + d], e);
    out[OUT_EMB + d] = e;
    emb[d] = e;
}

// ---------------- Stage 4a: h partial sums (16 blocks over d-slices) ---------
__global__ __launch_bounds__(256) void k_mlp1(
    const float* __restrict__ emb, const float* __restrict__ Wc1,
    float* __restrict__ hpart)
{
    __shared__ float se[64];
    const int b = blockIdx.x, tid = threadIdx.x;
    if (tid < 64) se[tid] = emb[b * 64 + tid];
    __syncthreads();
    float p = 0.f;
    #pragma unroll 8
    for (int d = 0; d < 64; ++d)
        p = fmaf(se[d], Wc1[(size_t)(b * 64 + d) * H_DIM + tid], p);
    hpart[b * H_DIM + tid] = p;
}

// ---------------- Stage 4b: relu + Wc2 dot + bias ----------------------------
__global__ __launch_bounds__(256) void k_logit(
    const float* __restrict__ hpart, const float* __restrict__ bc1,
    const float* __restrict__ Wc2, const float* __restrict__ bc2,
    float* __restrict__ out)
{
    __shared__ float red[256];
    const int tid = threadIdx.x;
    float h = bc1[tid];
    #pragma unroll
    for (int i = 0; i < 16; ++i) h += hpart[i * H_DIM + tid];
    h = fmaxf(h, 0.f) * Wc2[tid];
    red[tid] = h;
    __syncthreads();
    for (int off = 128; off > 0; off >>= 1) {
        if (tid < off) red[tid] += red[tid + off];
        __syncthreads();
    }
    if (tid == 0) out[OUT_LOGIT] = red[0] + bc2[0];
}

// ---------------- Launch ------------------------------------------------------
extern "C" void kernel_launch(void* const* d_in, const int* in_sizes, int n_in,
                              void* d_out, int out_size, void* d_ws, size_t ws_size,
                              hipStream_t stream)
{
    const float* x   = (const float*)d_in[0];
    const float* Wa1 = (const float*)d_in[1];
    const float* ba1 = (const float*)d_in[2];
    const float* Wa2 = (const float*)d_in[3];
    const float* ba2 = (const float*)d_in[4];
    const float* Wc1 = (const float*)d_in[5];
    const float* bc1 = (const float*)d_in[6];
    const float* Wc2 = (const float*)d_in[7];
    const float* bc2 = (const float*)d_in[8];
    float* out = (float*)d_out;
    float* ws  = (float*)d_ws;

    float* scores = ws + WS_SCORES;
    float* candv  = ws + WS_CANDV;
    int*   candi  = (int*)(ws + WS_CANDI);
    float* attn   = ws + WS_ATTN;
    int*   topi   = (int*)(ws + WS_TOPI);
    float* emb    = ws + WS_EMB;
    float* hpart  = ws + WS_HPART;
    uint4* wpk    = (uint4*)(ws + WS_WPK);

    dim3 blk(256);
    k_prepack<<<128, blk, 0, stream>>>(Wa1, wpk);
    k_scores<<<(N_PATCH + 127) / 128, blk, 0, stream>>>(x, wpk, ba1, Wa2, ba2, scores);
    k_topk_local<<<NB2A, blk, 0, stream>>>(scores, candv, candi, out + OUT_FW);
    k_topk_global<<<1, blk, 0, stream>>>(candv, candi, out, attn, topi);
    k_embed<<<4, blk, 0, stream>>>(x, attn, topi, out, emb);
    k_mlp1<<<16, blk, 0, stream>>>(emb, Wc1, hpart);
    k_logit<<<1, blk, 0, stream>>>(hpart, bc1, Wc2, bc2, out);
}

// Round 3
// 777.094 us; speedup vs baseline: 1.1825x; 1.0032x over previous
//
#include <hip/hip_runtime.h>
#include <cstddef>
#include <cstdint>

// Problem dims (fixed by reference setup_inputs)
#define N_PATCH 100000
#define D_IN    1024
#define A_DIM   128
#define H_DIM   256
#define KTOP    16

// d_out layout (fp32 flat, reference return order)
#define OUT_LOGIT 0
#define OUT_EMB   1
#define OUT_FW    (1 + D_IN)             // 1025
#define OUT_TOPI  (OUT_FW + N_PATCH)     // 101025

// workspace layout (float units)
#define WS_SCORES 0
#define WS_CANDV  (N_PATCH)                  // 100000
#define WS_CANDI  (N_PATCH + 4096)
#define WS_ATTN   (N_PATCH + 2 * 4096)       // 108192
#define WS_TOPI   (WS_ATTN + KTOP)           // 108208
#define WS_EMB    (WS_TOPI + KTOP)           // 108224
#define WS_HPART  (WS_EMB + D_IN)            // 109248  (16*256 floats)
#define WS_WPK    (WS_HPART + 16 * H_DIM)    // 113344  (512 KB = 131072 floats), 16B-aligned

// stage-2a config
#define NB2A  256
#define CHUNK 391   // ceil(100000/256)

typedef __attribute__((ext_vector_type(8))) short bf8_t;   // 8 bf16 (4 VGPRs)
typedef __attribute__((ext_vector_type(4))) float f4_t;    // MFMA C/D frag

// ---------------- Stage 0: prepack Wa1 -> hi/lo bf16 in B-fragment layout ----
// chunk t in [0, 32768): lane=t&63, part=(t>>6)&1, nt=(t>>7)&7, ks=t>>10
// chunk holds 8 bf16: element j -> W[k = ks*32 + (lane>>4)*8 + j][n = nt*16 + (lane&15)]
__global__ __launch_bounds__(256) void k_prepack(
    const float* __restrict__ Wa1, uint4* __restrict__ wpk)
{
    int t = blockIdx.x * 256 + threadIdx.x;     // grid 128 blocks -> 32768 chunks
    int lane = t & 63;
    int part = (t >> 6) & 1;
    int nt   = (t >> 7) & 7;
    int ks   = t >> 10;
    int n  = nt * 16 + (lane & 15);
    int k0 = ks * 32 + ((lane >> 4) * 8);
    union { ushort u[8]; uint4 v; } o;
    #pragma unroll
    for (int j = 0; j < 8; ++j) {
        float w = Wa1[(size_t)(k0 + j) * A_DIM + n];
        uint b = __float_as_uint(w);
        if (part == 0) {
            o.u[j] = (ushort)(b >> 16);                       // hi (truncated bf16)
        } else {
            float hf = __uint_as_float(b & 0xffff0000u);
            o.u[j] = (ushort)(__float_as_uint(w - hf) >> 16); // lo
        }
    }
    wpk[t] = o.v;
}

// ---------------- Stage 1: scores = tanh(x@Wa1+ba1)@Wa2 + ba2 (split-bf16 MFMA)
// Block: 256 thr = 4 waves; wave covers 32 rows x 128 cols; block = 128 rows.
__device__ __forceinline__ void split8(const float4& a, const float4& b,
                                       bf8_t& hi, bf8_t& lo)
{
    union { float f[8]; uint u[8]; float4 v4[2]; } X;
    X.v4[0] = a; X.v4[1] = b;
    union { uint u[4]; bf8_t v; } H, L;
    #pragma unroll
    for (int j = 0; j < 4; ++j) {
        uint x0 = X.u[2 * j], x1 = X.u[2 * j + 1];
        // low16 = top16(x0), high16 = top16(x1)
        H.u[j] = __builtin_amdgcn_perm(x1, x0, 0x07060302);
        float l0 = X.f[2 * j]     - __uint_as_float(x0 & 0xffff0000u);
        float l1 = X.f[2 * j + 1] - __uint_as_float(x1 & 0xffff0000u);
        L.u[j] = __builtin_amdgcn_perm(__float_as_uint(l1), __float_as_uint(l0), 0x07060302);
    }
    hi = H.v; lo = L.v;
}

#define MFMA_BF16 __builtin_amdgcn_mfma_f32_16x16x32_bf16

__global__ __launch_bounds__(256) void k_scores(
    const float* __restrict__ x, const uint4* __restrict__ wpk,
    const float* __restrict__ ba1, const float* __restrict__ Wa2,
    const float* __restrict__ ba2, float* __restrict__ scores)
{
    __shared__ uint4 sB[2][1024];   // 32 KB double buffer

    const int tid = threadIdx.x;
    const int ln  = tid & 63;
    const int q   = ln >> 4;      // k-quad
    const int c   = ln & 15;      // col selector (B) / row selector (A)
    const int wv  = tid >> 6;
    const int row0 = blockIdx.x * 128 + wv * 32;

    // A-stream pointers (fragment layout: row = c, k = q*8 + j)
    const int r0 = min(row0 + c,      N_PATCH - 1);
    const int r1 = min(row0 + 16 + c, N_PATCH - 1);
    const float* pa0 = x + (size_t)r0 * D_IN + q * 8;
    const float* pa1 = x + (size_t)r1 * D_IN + q * 8;

    f4_t acc[2][8];
    #pragma unroll
    for (int rt = 0; rt < 2; ++rt)
        #pragma unroll
        for (int nt = 0; nt < 8; ++nt)
            acc[rt][nt] = (f4_t){0.f, 0.f, 0.f, 0.f};

    // ---- prologue: stage B tile 0 into LDS, prefetch B tile 1 + A step 0 ----
    uint4 b0[4], bpre[4];
    #pragma unroll
    for (int i = 0; i < 4; ++i) b0[i] = wpk[tid + i * 256];
    #pragma unroll
    for (int i = 0; i < 4; ++i) sB[0][tid + i * 256] = b0[i];
    #pragma unroll
    for (int i = 0; i < 4; ++i) bpre[i] = wpk[1024 + tid + i * 256];

    float4 a_cur[4], a_nxt[4];
    a_cur[0] = *(const float4*)(pa0);
    a_cur[1] = *(const float4*)(pa0 + 4);
    a_cur[2] = *(const float4*)(pa1);
    a_cur[3] = *(const float4*)(pa1 + 4);

    __syncthreads();

    for (int ks = 0; ks < 32; ++ks) {
        const int cur = ks & 1;

        if (ks < 31) {
            // stage next B tile (other buffer; current readers unaffected)
            #pragma unroll
            for (int i = 0; i < 4; ++i) sB[cur ^ 1][tid + i * 256] = bpre[i];
            // prefetch A for ks+1 (in flight during this step's MFMAs)
            a_nxt[0] = *(const float4*)(pa0 + (ks + 1) * 32);
            a_nxt[1] = *(const float4*)(pa0 + (ks + 1) * 32 + 4);
            a_nxt[2] = *(const float4*)(pa1 + (ks + 1) * 32);
            a_nxt[3] = *(const float4*)(pa1 + (ks + 1) * 32 + 4);
        }
        if (ks < 30) {
            // prefetch B for ks+2
            #pragma unroll
            for (int i = 0; i < 4; ++i) bpre[i] = wpk[(ks + 2) * 1024 + tid + i * 256];
        }

        bf8_t ahi0, alo0, ahi1, alo1;
        split8(a_cur[0], a_cur[1], ahi0, alo0);
        split8(a_cur[2], a_cur[3], ahi1, alo1);

        const bf8_t* sBf = (const bf8_t*)sB[cur];
        // two column-tiles at a time -> 4 independent acc chains, dep distance 4
        #pragma unroll
        for (int nt = 0; nt < 8; nt += 2) {
            bf8_t bh0 = sBf[(nt * 2 + 0) * 64 + ln];
            bf8_t bl0 = sBf[(nt * 2 + 1) * 64 + ln];
            bf8_t bh1 = sBf[(nt * 2 + 2) * 64 + ln];
            bf8_t bl1 = sBf[(nt * 2 + 3) * 64 + ln];
            acc[0][nt]     = MFMA_BF16(ahi0, bh0, acc[0][nt],     0, 0, 0);
            acc[1][nt]     = MFMA_BF16(ahi1, bh0, acc[1][nt],     0, 0, 0);
            acc[0][nt + 1] = MFMA_BF16(ahi0, bh1, acc[0][nt + 1], 0, 0, 0);
            acc[1][nt + 1] = MFMA_BF16(ahi1, bh1, acc[1][nt + 1], 0, 0, 0);
            acc[0][nt]     = MFMA_BF16(alo0, bh0, acc[0][nt],     0, 0, 0);
            acc[1][nt]     = MFMA_BF16(alo1, bh0, acc[1][nt],     0, 0, 0);
            acc[0][nt + 1] = MFMA_BF16(alo0, bh1, acc[0][nt + 1], 0, 0, 0);
            acc[1][nt + 1] = MFMA_BF16(alo1, bh1, acc[1][nt + 1], 0, 0, 0);
            acc[0][nt]     = MFMA_BF16(ahi0, bl0, acc[0][nt],     0, 0, 0);
            acc[1][nt]     = MFMA_BF16(ahi1, bl0, acc[1][nt],     0, 0, 0);
            acc[0][nt + 1] = MFMA_BF16(ahi0, bl1, acc[0][nt + 1], 0, 0, 0);
            acc[1][nt + 1] = MFMA_BF16(ahi1, bl1, acc[1][nt + 1], 0, 0, 0);
        }

        #pragma unroll
        for (int i = 0; i < 4; ++i) a_cur[i] = a_nxt[i];
        __syncthreads();   // single barrier: next-buffer writes visible, cur reads done
    }

    // epilogue: +ba1, tanh, dot Wa2, reduce over the 16 lanes sharing rows
    float b1v[8], w2v[8];
    #pragma unroll
    for (int nt = 0; nt < 8; ++nt) {
        b1v[nt] = ba1[nt * 16 + c];
        w2v[nt] = Wa2[nt * 16 + c];
    }
    const float b2 = ba2[0];

    #pragma unroll
    for (int rt = 0; rt < 2; ++rt)
        #pragma unroll
        for (int reg = 0; reg < 4; ++reg) {
            float p = 0.f;
            #pragma unroll
            for (int nt = 0; nt < 8; ++nt)
                p += tanhf(acc[rt][nt][reg] + b1v[nt]) * w2v[nt];
            #pragma unroll
            for (int off = 1; off < 16; off <<= 1)
                p += __shfl_xor(p, off, 64);
            if (c == 0) {
                int row = row0 + rt * 16 + q * 4 + reg;   // C/D: row = quad*4+reg
                if (row < N_PATCH) scores[row] = p + b2;
            }
        }
}

// ---------------- Stage 2a: per-block local top-16 + zero full_weights -------
__global__ __launch_bounds__(256) void k_topk_local(
    const float* __restrict__ scores, float* __restrict__ candv,
    int* __restrict__ candi, float* __restrict__ out_fw)
{
    __shared__ float sv[512];
    __shared__ float rv[256];
    __shared__ int   rs[256];
    const int tid  = threadIdx.x;
    const int base = blockIdx.x * CHUNK;

    for (int i = tid; i < 512; i += 256) {
        int g = base + i;
        sv[i] = (i < CHUNK && g < N_PATCH) ? scores[g] : -1e30f;
    }
    for (int i = tid; i < CHUNK; i += 256) {
        int g = base + i;
        if (g < N_PATCH) out_fw[g] = 0.f;   // zero full_weights (d_out is poisoned)
    }
    __syncthreads();

    for (int r = 0; r < KTOP; ++r) {
        float v1 = sv[tid], v2 = sv[tid + 256];
        float bv; int bs;
        if (v2 > v1) { bv = v2; bs = tid + 256; } else { bv = v1; bs = tid; }
        rv[tid] = bv; rs[tid] = bs;
        __syncthreads();
        for (int off = 128; off > 0; off >>= 1) {
            if (tid < off) {
                float ov = rv[tid + off]; int os = rs[tid + off];
                if (ov > rv[tid] || (ov == rv[tid] && os < rs[tid])) {
                    rv[tid] = ov; rs[tid] = os;
                }
            }
            __syncthreads();
        }
        if (tid == 0) {
            int s = rs[0];
            candv[blockIdx.x * KTOP + r] = rv[0];
            candi[blockIdx.x * KTOP + r] = base + s;
            sv[s] = -1e30f;
        }
        __syncthreads();
    }
}

// ---------------- Stage 2b: global top-16, softmax, scatter ------------------
__global__ __launch_bounds__(256) void k_topk_global(
    const float* __restrict__ candv, const int* __restrict__ candi,
    float* __restrict__ out, float* __restrict__ ws_attn, int* __restrict__ ws_topi)
{
    __shared__ float cv[4096];
    __shared__ int   ci[4096];
    __shared__ float rv[256];
    __shared__ int   rgx[256];
    __shared__ int   rsl[256];
    __shared__ float topv[KTOP];
    __shared__ int   topi[KTOP];
    __shared__ float attn[KTOP];
    const int tid = threadIdx.x;

    for (int i = tid; i < 4096; i += 256) { cv[i] = candv[i]; ci[i] = candi[i]; }
    __syncthreads();

    for (int r = 0; r < KTOP; ++r) {
        float bv = -1e38f; int bg = 0x7fffffff; int bs = tid * 16;
        #pragma unroll
        for (int i = 0; i < 16; ++i) {
            int s = tid * 16 + i;
            float v = cv[s]; int g = ci[s];
            if (v > bv || (v == bv && g < bg)) { bv = v; bg = g; bs = s; }
        }
        rv[tid] = bv; rgx[tid] = bg; rsl[tid] = bs;
        __syncthreads();
        for (int off = 128; off > 0; off >>= 1) {
            if (tid < off) {
                if (rv[tid + off] > rv[tid] ||
                    (rv[tid + off] == rv[tid] && rgx[tid + off] < rgx[tid])) {
                    rv[tid] = rv[tid + off]; rgx[tid] = rgx[tid + off]; rsl[tid] = rsl[tid + off];
                }
            }
            __syncthreads();
        }
        if (tid == 0) {
            topv[r] = rv[0]; topi[r] = rgx[0]; cv[rsl[0]] = -1e30f;
        }
        __syncthreads();
    }

    if (tid == 0) {
        float mx = topv[0];
        float s = 0.f;
        for (int k2 = 0; k2 < KTOP; ++k2) {
            float e = expf(topv[k2] - mx);
            attn[k2] = e; s += e;
        }
        float inv = 1.f / s;
        for (int k2 = 0; k2 < KTOP; ++k2) attn[k2] *= inv;
    }
    __syncthreads();

    if (tid < KTOP) {
        out[OUT_TOPI + tid] = (float)topi[tid];
        out[OUT_FW + topi[tid]] = attn[tid];
        ws_attn[tid] = attn[tid];
        ws_topi[tid] = topi[tid];
    }
}

// ---------------- Stage 3: slide_embedding = attn_w @ x[top_idx] -------------
__global__ __launch_bounds__(256) void k_embed(
    const float* __restrict__ x, const float* __restrict__ attn,
    const int* __restrict__ topi, float* __restrict__ out, float* __restrict__ emb)
{
    __shared__ float a[KTOP];
    __shared__ int   ti[KTOP];
    if (threadIdx.x < KTOP) { a[threadIdx.x] = attn[threadIdx.x]; ti[threadIdx.x] = topi[threadIdx.x]; }
    __syncthreads();
    int d = blockIdx.x * 256 + threadIdx.x;   // grid = 4 -> 1024 dims
    float e = 0.f;
    #pragma unroll
    for (int k2 = 0; k2 < KTOP; ++k2)
        e = fmaf(a[k2], x[(size_t)ti[k2] * D_IN + d], e);
    out[OUT_EMB + d] = e;
    emb[d] = e;
}

// ---------------- Stage 4a: h partial sums (16 blocks over d-slices) ---------
__global__ __launch_bounds__(256) void k_mlp1(
    const float* __restrict__ emb, const float* __restrict__ Wc1,
    float* __restrict__ hpart)
{
    __shared__ float se[64];
    const int b = blockIdx.x, tid = threadIdx.x;
    if (tid < 64) se[tid] = emb[b * 64 + tid];
    __syncthreads();
    float p = 0.f;
    #pragma unroll 8
    for (int d = 0; d < 64; ++d)
        p = fmaf(se[d], Wc1[(size_t)(b * 64 + d) * H_DIM + tid], p);
    hpart[b * H_DIM + tid] = p;
}

// ---------------- Stage 4b: relu + Wc2 dot + bias ----------------------------
__global__ __launch_bounds__(256) void k_logit(
    const float* __restrict__ hpart, const float* __restrict__ bc1,
    const float* __restrict__ Wc2, const float* __restrict__ bc2,
    float* __restrict__ out)
{
    __shared__ float red[256];
    const int tid = threadIdx.x;
    float h = bc1[tid];
    #pragma unroll
    for (int i = 0; i < 16; ++i) h += hpart[i * H_DIM + tid];
    h = fmaxf(h, 0.f) * Wc2[tid];
    red[tid] = h;
    __syncthreads();
    for (int off = 128; off > 0; off >>= 1) {
        if (tid < off) red[tid] += red[tid + off];
        __syncthreads();
    }
    if (tid == 0) out[OUT_LOGIT] = red[0] + bc2[0];
}

// ---------------- Launch ------------------------------------------------------
extern "C" void kernel_launch(void* const* d_in, const int* in_sizes, int n_in,
                              void* d_out, int out_size, void* d_ws, size_t ws_size,
                              hipStream_t stream)
{
    const float* x   = (const float*)d_in[0];
    const float* Wa1 = (const float*)d_in[1];
    const float* ba1 = (const float*)d_in[2];
    const float* Wa2 = (const float*)d_in[3];
    const float* ba2 = (const float*)d_in[4];
    const float* Wc1 = (const float*)d_in[5];
    const float* bc1 = (const float*)d_in[6];
    const float* Wc2 = (const float*)d_in[7];
    const float* bc2 = (const float*)d_in[8];
    float* out = (float*)d_out;
    float* ws  = (float*)d_ws;

    float* scores = ws + WS_SCORES;
    float* candv  = ws + WS_CANDV;
    int*   candi  = (int*)(ws + WS_CANDI);
    float* attn   = ws + WS_ATTN;
    int*   topi   = (int*)(ws + WS_TOPI);
    float* emb    = ws + WS_EMB;
    float* hpart  = ws + WS_HPART;
    uint4* wpk    = (uint4*)(ws + WS_WPK);

    dim3 blk(256);
    k_prepack<<<128, blk, 0, stream>>>(Wa1, wpk);
    k_scores<<<(N_PATCH + 127) / 128, blk, 0, stream>>>(x, wpk, ba1, Wa2, ba2, scores);
    k_topk_local<<<NB2A, blk, 0, stream>>>(scores, candv, candi, out + OUT_FW);
    k_topk_global<<<1, blk, 0, stream>>>(candv, candi, out, attn, topi);
    k_embed<<<4, blk, 0, stream>>>(x, attn, topi, out, emb);
    k_mlp1<<<16, blk, 0, stream>>>(emb, Wc1, hpart);
    k_logit<<<1, blk, 0, stream>>>(hpart, bc1, Wc2, bc2, out);
}